// Round 6
// baseline (269.314 us; speedup 1.0000x reference)
//
#include <hip/hip_runtime.h>
#include <hip/hip_bf16.h>
#include <hip/hip_fp16.h>

// GAT 2-layer forward for MI355X — round 6.
// Changes vs round 5 (safe structural round):
//  - hbuf (layer-1 output) stored fp16: halves node1-write + gemm2-read traffic.
//  - gemm_att layer1 ROWS=32 (halves W1 L2 traffic, 2x ILP), guarded tails.
//  - node_kernel: 256-thread blocks covering NPB nodes (2 for H=2, 4 for H=1).
//  - zero_small replaced by hipMemsetAsync.

#define SLOPE 0.2f
static __device__ __forceinline__ float lrelu(float a) { return a > 0.f ? a : SLOPE * a; }

#define NBK_MAX 256  // max buckets (N <= 65536)

// ---------------- CSR build (bucketed) ----------------

__global__ void bucket_hist(const int* __restrict__ dst, int* __restrict__ bucket_count,
                            int E, int nbk) {
  __shared__ int h[NBK_MAX];
  for (int i = threadIdx.x; i < nbk; i += blockDim.x) h[i] = 0;
  __syncthreads();
  int stride = gridDim.x * blockDim.x;
  for (int e = blockIdx.x * blockDim.x + threadIdx.x; e < E; e += stride)
    atomicAdd(&h[dst[e] >> 8], 1);
  __syncthreads();
  for (int i = threadIdx.x; i < nbk; i += blockDim.x)
    if (h[i]) atomicAdd(&bucket_count[i], h[i]);
}

__global__ void bucket_scan(const int* __restrict__ bucket_count, int* __restrict__ bucket_base,
                            int* __restrict__ bucket_cursor, int nbk, int Etot) {
  __shared__ int sh[256];
  int t = threadIdx.x;
  int v = (t < nbk) ? bucket_count[t] : 0;
  sh[t] = v;
  __syncthreads();
  for (int o = 1; o < 256; o <<= 1) {
    int u = (t >= o) ? sh[t - o] : 0;
    __syncthreads();
    sh[t] += u;
    __syncthreads();
  }
  int excl = sh[t] - v;
  if (t < nbk) { bucket_base[t] = excl; bucket_cursor[t] = excl; }
  if (t == 0) bucket_base[nbk] = Etot;
}

template <int CHUNK>  // 8192 = 256 threads x 32
__global__ void bin_kernel(const int* __restrict__ src, const int* __restrict__ dst,
                           int* __restrict__ bucket_cursor, unsigned int* __restrict__ binned,
                           int E, int nbk) {
  constexpr int PT = CHUNK / 256;
  __shared__ int hist[NBK_MAX];
  __shared__ int lbase[NBK_MAX];
  __shared__ int lcur[NBK_MAX];
  __shared__ int gpos[NBK_MAX];
  __shared__ unsigned int stage[CHUNK];
  __shared__ int sh[256];
  int t = threadIdx.x;
  int e0 = blockIdx.x * CHUNK;
  int cnt = min(CHUNK, E - e0);

  for (int i = t; i < nbk; i += 256) hist[i] = 0;
  __syncthreads();

  unsigned int pk[PT];
#pragma unroll
  for (int i = 0; i < PT; i++) {
    int e = e0 + t + i * 256;
    if (e < E) {
      int s = src[e], d = dst[e];
      int b = d >> 8;
      pk[i] = ((unsigned)b << 24) | ((unsigned)s << 8) | (unsigned)(d & 255);
      atomicAdd(&hist[b], 1);
    } else {
      pk[i] = 0xFFFFFFFFu;
    }
  }
  __syncthreads();

  int hv = (t < nbk) ? hist[t] : 0;
  sh[t] = hv;
  __syncthreads();
  for (int o = 1; o < 256; o <<= 1) {
    int u = (t >= o) ? sh[t - o] : 0;
    __syncthreads();
    sh[t] += u;
    __syncthreads();
  }
  if (t < nbk) {
    lbase[t] = sh[t] - hv;
    lcur[t] = sh[t] - hv;
    gpos[t] = hv ? atomicAdd(&bucket_cursor[t], hv) : 0;
  }
  __syncthreads();

#pragma unroll
  for (int i = 0; i < PT; i++) {
    if (pk[i] != 0xFFFFFFFFu) {
      int b = pk[i] >> 24;
      int lp = atomicAdd(&lcur[b], 1);
      stage[lp] = pk[i];
    }
  }
  __syncthreads();

  for (int i = t; i < cnt; i += 256) {
    unsigned int v = stage[i];
    int b = v >> 24;
    binned[gpos[b] + (i - lbase[b])] = v;
  }
}

template <int CAP>  // 12288
__global__ void build_kernel(const unsigned int* __restrict__ binned,
                             const int* __restrict__ bucket_base, int* __restrict__ offsets,
                             int* __restrict__ csr_src, int Nn, int Etot, int nbk) {
  __shared__ int nhist[256];
  __shared__ int sh[256];
  __shared__ int lcur[256];
  __shared__ unsigned short stage[CAP];
  int b = blockIdx.x;
  int t = threadIdx.x;
  int base = bucket_base[b];
  int sz = bucket_base[b + 1] - base;

  nhist[t] = 0;
  __syncthreads();
  for (int i = t; i < sz; i += 256) atomicAdd(&nhist[binned[base + i] & 255], 1);
  __syncthreads();

  int hv = nhist[t];
  sh[t] = hv;
  __syncthreads();
  for (int o = 1; o < 256; o <<= 1) {
    int u = (t >= o) ? sh[t - o] : 0;
    __syncthreads();
    sh[t] += u;
    __syncthreads();
  }
  int excl = sh[t] - hv;
  int node = (b << 8) + t;
  if (node < Nn) offsets[node] = base + excl;
  if (b == nbk - 1 && t == 0) offsets[Nn] = Etot;
  lcur[t] = excl;
  __syncthreads();

  if (sz <= CAP) {
    for (int i = t; i < sz; i += 256) {
      unsigned int v = binned[base + i];
      int lp = atomicAdd(&lcur[v & 255], 1);
      stage[lp] = (unsigned short)((v >> 8) & 0xFFFFu);
    }
    __syncthreads();
    for (int i = t; i < sz; i += 256) csr_src[base + i] = (int)stage[i];
  } else {
    for (int i = t; i < sz; i += 256) {
      unsigned int v = binned[base + i];
      int lp = atomicAdd(&lcur[v & 255], 1);
      csr_src[base + lp] = (int)((v >> 8) & 0xFFFFu);
    }
  }
}

// ---------------- GEMM + fused attention dots (fp16 feature output) ----------------

// A dtype templated: float (layer 1 input) or __half (layer-1 output hbuf).
template <int K, int NC, int ROWS, int H, typename AT>
__global__ void gemm_att(const AT* __restrict__ X, const float* __restrict__ W,
                         const float* __restrict__ att_s, const float* __restrict__ att_d,
                         __half* __restrict__ YH, float* __restrict__ AS, float* __restrict__ AD,
                         int Nrows) {
  __shared__ float xs[ROWS * K];
  int r0 = blockIdx.x * ROWS;
  int t = threadIdx.x;
  int h = t >> 6;
  int lane = t & 63;

  // stage ROWS x K into fp32 LDS (guarded tail rows -> 0)
  if constexpr (sizeof(AT) == 4) {
    const float4* X4 = (const float4*)X;
    for (int i = t; i < ROWS * K / 4; i += NC) {
      int r = i / (K / 4);
      int gr = r0 + r;
      float4 v = make_float4(0.f, 0.f, 0.f, 0.f);
      if (gr < Nrows) v = X4[(size_t)gr * (K / 4) + (i - r * (K / 4))];
      ((float4*)xs)[i] = v;
    }
  } else {
    const uint4* X8 = (const uint4*)X;  // 8 halfs
    for (int i = t; i < ROWS * K / 8; i += NC) {
      int r = i / (K / 8);
      int gr = r0 + r;
      float f[8];
      if (gr < Nrows) {
        uint4 u = X8[(size_t)gr * (K / 8) + (i - r * (K / 8))];
        float2 f0 = __half22float2(*(const __half2*)&u.x);
        float2 f1 = __half22float2(*(((const __half2*)&u.x) + 1));
        float2 f2 = __half22float2(*(const __half2*)&u.z);
        float2 f3 = __half22float2(*(((const __half2*)&u.z) + 1));
        f[0] = f0.x; f[1] = f0.y; f[2] = f1.x; f[3] = f1.y;
        f[4] = f2.x; f[5] = f2.y; f[6] = f3.x; f[7] = f3.y;
      } else {
#pragma unroll
        for (int k = 0; k < 8; k++) f[k] = 0.f;
      }
#pragma unroll
      for (int k = 0; k < 8; k++) xs[i * 8 + k] = f[k];
    }
  }
  __syncthreads();

  float acc[ROWS];
#pragma unroll
  for (int r = 0; r < ROWS; r++) acc[r] = 0.f;
  for (int k = 0; k < K; k++) {
    float w = W[k * NC + t];
#pragma unroll
    for (int r = 0; r < ROWS; r++) acc[r] = fmaf(xs[r * K + k], w, acc[r]);
  }

  float asw = att_s[t];
  float adw = att_d[t];
#pragma unroll
  for (int r = 0; r < ROWS; r++) {
    int gr = r0 + r;
    float ps = acc[r] * asw;
    float pd = acc[r] * adw;
    for (int o = 32; o > 0; o >>= 1) {
      ps += __shfl_xor(ps, o);
      pd += __shfl_xor(pd, o);
    }
    if (gr < Nrows) {
      YH[(size_t)gr * NC + t] = __float2half(acc[r]);
      if (lane == 0) {
        AS[gr * H + h] = ps;
        AD[gr * H + h] = pd;
      }
    }
  }
}

// ---------------- node softmax + aggregate ----------------

static __device__ __forceinline__ void fma8(uint4 u, float e, float* __restrict__ acc) {
  float2 f0 = __half22float2(*(const __half2*)&u.x);
  float2 f1 = __half22float2(*(((const __half2*)&u.x) + 1));
  float2 f2 = __half22float2(*(const __half2*)&u.z);
  float2 f3 = __half22float2(*(((const __half2*)&u.z) + 1));
  acc[0] = fmaf(e, f0.x, acc[0]); acc[1] = fmaf(e, f0.y, acc[1]);
  acc[2] = fmaf(e, f1.x, acc[2]); acc[3] = fmaf(e, f1.y, acc[3]);
  acc[4] = fmaf(e, f2.x, acc[4]); acc[5] = fmaf(e, f2.y, acc[5]);
  acc[6] = fmaf(e, f3.x, acc[6]); acc[7] = fmaf(e, f3.y, acc[7]);
}

// 256-thread blocks, 4 waves; wave w handles node blockIdx*NPB + w/H, head w%H.
// Within a wave: 8 groups of 8 lanes; lane owns 8 channels (one dwordx4 fp16).
template <int H, int NPB, bool RELU, typename OT>
__global__ void node_kernel(const int* __restrict__ offsets, const int* __restrict__ csr_src,
                            const float* __restrict__ AS, const float* __restrict__ AD,
                            const __half* __restrict__ XPH, const float* __restrict__ bias,
                            OT* __restrict__ OUT, int Nn) {
  constexpr int C = 64;
  constexpr int ROWH = H * C;  // halfs per feature row
  int w = threadIdx.x >> 6;
  int n = blockIdx.x * NPB + (w / H);
  int h = w % H;
  if (n >= Nn) return;  // wave-uniform
  int lane = threadIdx.x & 63;
  int g = lane >> 3;   // edge group 0..7
  int sub = lane & 7;  // 16-B channel block

  int beg = offsets[n], end = offsets[n + 1];
  int deg = end - beg;

  float ad_n = AD[n * H + h];
  const __half* base = XPH + h * C + sub * 8;

  float acc[8];
#pragma unroll
  for (int k = 0; k < 8; k++) acc[k] = 0.f;
  float z = 0.f;

  float e_self = __expf(lrelu(AS[n * H + h] + ad_n));
  if (g == 0) {
    uint4 u = *(const uint4*)(base + (size_t)n * ROWH);
    fma8(u, e_self, acc);
  }
  if (lane == 0) z = e_self;

  for (int i0 = 0; i0 < deg; i0 += 64) {
    int cnt = min(64, deg - i0);
    int srcv = 0;
    float ev = 0.f;
    if (lane < cnt) {
      srcv = csr_src[beg + i0 + lane];
      ev = __expf(lrelu(AS[srcv * H + h] + ad_n));
    }
    z += ev;
    int j = 0;
    for (; j + 32 <= cnt; j += 32) {
      int s0 = __shfl(srcv, j + g),      s1 = __shfl(srcv, j + 8 + g);
      int s2 = __shfl(srcv, j + 16 + g), s3 = __shfl(srcv, j + 24 + g);
      float e0 = __shfl(ev, j + g),      e1 = __shfl(ev, j + 8 + g);
      float e2 = __shfl(ev, j + 16 + g), e3 = __shfl(ev, j + 24 + g);
      uint4 u0 = *(const uint4*)(base + (size_t)s0 * ROWH);
      uint4 u1 = *(const uint4*)(base + (size_t)s1 * ROWH);
      uint4 u2 = *(const uint4*)(base + (size_t)s2 * ROWH);
      uint4 u3 = *(const uint4*)(base + (size_t)s3 * ROWH);
      fma8(u0, e0, acc);
      fma8(u1, e1, acc);
      fma8(u2, e2, acc);
      fma8(u3, e3, acc);
    }
    for (; j + 8 <= cnt; j += 8) {
      int s = __shfl(srcv, j + g);
      float e = __shfl(ev, j + g);
      uint4 u = *(const uint4*)(base + (size_t)s * ROWH);
      fma8(u, e, acc);
    }
    if (j < cnt) {
      int idx = j + g;
      int s = __shfl(srcv, idx & 63);
      float e = __shfl(ev, idx & 63);
      if (idx < cnt) {
        uint4 u = *(const uint4*)(base + (size_t)s * ROWH);
        fma8(u, e, acc);
      }
    }
  }

#pragma unroll
  for (int o = 8; o <= 32; o <<= 1) {
#pragma unroll
    for (int k = 0; k < 8; k++) acc[k] += __shfl_xor(acc[k], o);
  }
  for (int o = 32; o > 0; o >>= 1) z += __shfl_xor(z, o);
  float inv = 1.0f / z;

  if (g == 0) {
    const float* bp = bias + h * C + sub * 8;
    float r[8];
#pragma unroll
    for (int k = 0; k < 8; k++) {
      r[k] = fmaf(acc[k], inv, bp[k]);
      if (RELU) r[k] = fmaxf(r[k], 0.f);
    }
    if constexpr (sizeof(OT) == 4) {
      float* op = (float*)OUT + (size_t)n * ROWH + h * C + sub * 8;
      ((float4*)op)[0] = make_float4(r[0], r[1], r[2], r[3]);
      ((float4*)op)[1] = make_float4(r[4], r[5], r[6], r[7]);
    } else {
      __half* op = (__half*)OUT + (size_t)n * ROWH + h * C + sub * 8;
      __half2 h0 = __floats2half2_rn(r[0], r[1]);
      __half2 h1 = __floats2half2_rn(r[2], r[3]);
      __half2 h2 = __floats2half2_rn(r[4], r[5]);
      __half2 h3 = __floats2half2_rn(r[6], r[7]);
      uint4 u;
      u.x = *(unsigned int*)&h0; u.y = *(unsigned int*)&h1;
      u.z = *(unsigned int*)&h2; u.w = *(unsigned int*)&h3;
      *(uint4*)op = u;
    }
  }
}

// ---------------- launch ----------------

static inline size_t alignup(size_t x) { return (x + 255) & ~(size_t)255; }

extern "C" void kernel_launch(void* const* d_in, const int* in_sizes, int n_in,
                              void* d_out, int out_size, void* d_ws, size_t ws_size,
                              hipStream_t stream) {
  const float* x    = (const float*)d_in[0];
  const int*   edges= (const int*)d_in[1];
  const float* W1   = (const float*)d_in[2];
  const float* as1w = (const float*)d_in[3];
  const float* ad1w = (const float*)d_in[4];
  const float* b1   = (const float*)d_in[5];
  const float* W2   = (const float*)d_in[6];
  const float* as2w = (const float*)d_in[7];
  const float* ad2w = (const float*)d_in[8];
  const float* b2   = (const float*)d_in[9];

  const int N = in_sizes[0] / 128;   // 50000
  const int E = in_sizes[1] / 2;     // 1600000
  const int* src = edges;
  const int* dst = edges + E;
  const int nbk = (N + 255) >> 8;    // 196 buckets

  char* p = (char*)d_ws;
  size_t off = 0;
  auto take = [&](size_t bytes) { char* r = p + off; off = alignup(off + bytes); return r; };
  __half* xph1 = (__half*)take((size_t)N * 128 * 2);
  __half* xph2 = (__half*)take((size_t)N * 64 * 2);
  __half* hbuf = (__half*)take((size_t)N * 128 * 2);
  float* as1   = (float*)take((size_t)N * 2 * 4);
  float* ad1   = (float*)take((size_t)N * 2 * 4);
  float* as2   = (float*)take((size_t)N * 4);
  float* ad2   = (float*)take((size_t)N * 4);
  int* offsets = (int*)take((size_t)(N + 1) * 4);
  int* csr_src = (int*)take((size_t)E * 4);
  unsigned int* binned = (unsigned int*)take((size_t)E * 4);
  int* bcount  = (int*)take((size_t)(nbk + 1) * 4);
  int* bbase   = (int*)take((size_t)(nbk + 1) * 4);
  int* bcursor = (int*)take((size_t)(nbk + 1) * 4);
  (void)ws_size;

  constexpr int CHUNK = 8192;
  const int binBlocks = (E + CHUNK - 1) / CHUNK;

  hipMemsetAsync(bcount, 0, (size_t)(nbk + 1) * 4, stream);
  bucket_hist<<<392, 256, 0, stream>>>(dst, bcount, E, nbk);
  bucket_scan<<<1, 256, 0, stream>>>(bcount, bbase, bcursor, nbk, E);
  bin_kernel<CHUNK><<<binBlocks, 256, 0, stream>>>(src, dst, bcursor, binned, E, nbk);
  build_kernel<12288><<<nbk, 256, 0, stream>>>(binned, bbase, offsets, csr_src, N, E, nbk);

  // layer 1 (H=2, C=64, ReLU) — x fp32 in, features fp16 out
  gemm_att<128, 128, 32, 2, float><<<(N + 31) / 32, 128, 0, stream>>>(
      x, W1, as1w, ad1w, xph1, as1, ad1, N);
  node_kernel<2, 2, true, __half><<<(N + 1) / 2, 256, 0, stream>>>(
      offsets, csr_src, as1, ad1, xph1, b1, hbuf, N);

  // layer 2 (H=1, C=64) — hbuf fp16 in, out fp32 to d_out
  gemm_att<128, 64, 16, 1, __half><<<(N + 15) / 16, 64, 0, stream>>>(
      hbuf, W2, as2w, ad2w, xph2, as2, ad2, N);
  node_kernel<1, 4, false, float><<<(N + 3) / 4, 256, 0, stream>>>(
      offsets, csr_src, as2, ad2, xph2, b2, (float*)d_out, N);
}

// Round 7
// 194.997 us; speedup vs baseline: 1.3811x; 1.3811x over previous
//
#include <hip/hip_runtime.h>
#include <hip/hip_bf16.h>
#include <hip/hip_fp16.h>

// GAT 2-layer forward for MI355X — round 7.
// Change vs round 6: both GEMMs moved to MFMA (v_mfma_f32_16x16x32_f16).
//  - xpose_w: W1/W2 -> fp16 W^T [NOUT][K] (coalesced writes, one-time ~64KB).
//  - gemm_att_mfma: 4 waves x 16 rows/block; A-frags direct from global
//    (fp32 x converted in-register for layer 1, fp16 hbuf for layer 2);
//    B-frags from +8-half padded LDS copy of W^T; att dots computed from
//    fp32 accumulators in-register; Y staged via LDS -> coalesced stores.
//  - CSR build and node kernels unchanged from r6 (node blocks NPB, hbuf fp16).

#define SLOPE 0.2f
static __device__ __forceinline__ float lrelu(float a) { return a > 0.f ? a : SLOPE * a; }

#define NBK_MAX 256  // max buckets (N <= 65536)

typedef _Float16 half8 __attribute__((ext_vector_type(8)));
typedef float f32x4 __attribute__((ext_vector_type(4)));

// ---------------- CSR build (bucketed) ----------------

__global__ void bucket_hist(const int* __restrict__ dst, int* __restrict__ bucket_count,
                            int E, int nbk) {
  __shared__ int h[NBK_MAX];
  for (int i = threadIdx.x; i < nbk; i += blockDim.x) h[i] = 0;
  __syncthreads();
  int stride = gridDim.x * blockDim.x;
  for (int e = blockIdx.x * blockDim.x + threadIdx.x; e < E; e += stride)
    atomicAdd(&h[dst[e] >> 8], 1);
  __syncthreads();
  for (int i = threadIdx.x; i < nbk; i += blockDim.x)
    if (h[i]) atomicAdd(&bucket_count[i], h[i]);
}

__global__ void bucket_scan(const int* __restrict__ bucket_count, int* __restrict__ bucket_base,
                            int* __restrict__ bucket_cursor, int nbk, int Etot) {
  __shared__ int sh[256];
  int t = threadIdx.x;
  int v = (t < nbk) ? bucket_count[t] : 0;
  sh[t] = v;
  __syncthreads();
  for (int o = 1; o < 256; o <<= 1) {
    int u = (t >= o) ? sh[t - o] : 0;
    __syncthreads();
    sh[t] += u;
    __syncthreads();
  }
  int excl = sh[t] - v;
  if (t < nbk) { bucket_base[t] = excl; bucket_cursor[t] = excl; }
  if (t == 0) bucket_base[nbk] = Etot;
}

template <int CHUNK>  // 8192 = 256 threads x 32
__global__ void bin_kernel(const int* __restrict__ src, const int* __restrict__ dst,
                           int* __restrict__ bucket_cursor, unsigned int* __restrict__ binned,
                           int E, int nbk) {
  constexpr int PT = CHUNK / 256;
  __shared__ int hist[NBK_MAX];
  __shared__ int lbase[NBK_MAX];
  __shared__ int lcur[NBK_MAX];
  __shared__ int gpos[NBK_MAX];
  __shared__ unsigned int stage[CHUNK];
  __shared__ int sh[256];
  int t = threadIdx.x;
  int e0 = blockIdx.x * CHUNK;
  int cnt = min(CHUNK, E - e0);

  for (int i = t; i < nbk; i += 256) hist[i] = 0;
  __syncthreads();

  unsigned int pk[PT];
#pragma unroll
  for (int i = 0; i < PT; i++) {
    int e = e0 + t + i * 256;
    if (e < E) {
      int s = src[e], d = dst[e];
      int b = d >> 8;
      pk[i] = ((unsigned)b << 24) | ((unsigned)s << 8) | (unsigned)(d & 255);
      atomicAdd(&hist[b], 1);
    } else {
      pk[i] = 0xFFFFFFFFu;
    }
  }
  __syncthreads();

  int hv = (t < nbk) ? hist[t] : 0;
  sh[t] = hv;
  __syncthreads();
  for (int o = 1; o < 256; o <<= 1) {
    int u = (t >= o) ? sh[t - o] : 0;
    __syncthreads();
    sh[t] += u;
    __syncthreads();
  }
  if (t < nbk) {
    lbase[t] = sh[t] - hv;
    lcur[t] = sh[t] - hv;
    gpos[t] = hv ? atomicAdd(&bucket_cursor[t], hv) : 0;
  }
  __syncthreads();

#pragma unroll
  for (int i = 0; i < PT; i++) {
    if (pk[i] != 0xFFFFFFFFu) {
      int b = pk[i] >> 24;
      int lp = atomicAdd(&lcur[b], 1);
      stage[lp] = pk[i];
    }
  }
  __syncthreads();

  for (int i = t; i < cnt; i += 256) {
    unsigned int v = stage[i];
    int b = v >> 24;
    binned[gpos[b] + (i - lbase[b])] = v;
  }
}

template <int CAP>  // 12288
__global__ void build_kernel(const unsigned int* __restrict__ binned,
                             const int* __restrict__ bucket_base, int* __restrict__ offsets,
                             int* __restrict__ csr_src, int Nn, int Etot, int nbk) {
  __shared__ int nhist[256];
  __shared__ int sh[256];
  __shared__ int lcur[256];
  __shared__ unsigned short stage[CAP];
  int b = blockIdx.x;
  int t = threadIdx.x;
  int base = bucket_base[b];
  int sz = bucket_base[b + 1] - base;

  nhist[t] = 0;
  __syncthreads();
  for (int i = t; i < sz; i += 256) atomicAdd(&nhist[binned[base + i] & 255], 1);
  __syncthreads();

  int hv = nhist[t];
  sh[t] = hv;
  __syncthreads();
  for (int o = 1; o < 256; o <<= 1) {
    int u = (t >= o) ? sh[t - o] : 0;
    __syncthreads();
    sh[t] += u;
    __syncthreads();
  }
  int excl = sh[t] - hv;
  int node = (b << 8) + t;
  if (node < Nn) offsets[node] = base + excl;
  if (b == nbk - 1 && t == 0) offsets[Nn] = Etot;
  lcur[t] = excl;
  __syncthreads();

  if (sz <= CAP) {
    for (int i = t; i < sz; i += 256) {
      unsigned int v = binned[base + i];
      int lp = atomicAdd(&lcur[v & 255], 1);
      stage[lp] = (unsigned short)((v >> 8) & 0xFFFFu);
    }
    __syncthreads();
    for (int i = t; i < sz; i += 256) csr_src[base + i] = (int)stage[i];
  } else {
    for (int i = t; i < sz; i += 256) {
      unsigned int v = binned[base + i];
      int lp = atomicAdd(&lcur[v & 255], 1);
      csr_src[base + lp] = (int)((v >> 8) & 0xFFFFu);
    }
  }
}

// ---------------- weight transpose to fp16 ----------------

// block 0: W1 [128][128] -> WT1 [128][128];  block 1: W2 [128][64] -> WT2 [64][128]
__global__ void xpose_w(const float* __restrict__ W1, const float* __restrict__ W2,
                        __half* __restrict__ WT1, __half* __restrict__ WT2) {
  int t = threadIdx.x;
  if (blockIdx.x == 0) {
    for (int idx = t; idx < 128 * 128; idx += 256) {
      int c = idx >> 7, k = idx & 127;
      WT1[idx] = __float2half(W1[k * 128 + c]);
    }
  } else {
    for (int idx = t; idx < 64 * 128; idx += 256) {
      int c = idx >> 7, k = idx & 127;
      WT2[idx] = __float2half(W2[k * 64 + c]);
    }
  }
}

// ---------------- MFMA GEMM + fused attention dots ----------------

// Block: 256 threads = 4 waves, each wave computes 16 rows x NOUT cols.
// A-frags direct from global (lane: row = l&15, k-chunk = (l>>4)*8).
// B-frags from padded LDS copy of WT ([NOUT][K+8] halfs).
// C/D layout (verified): col = lane&15, row = (lane>>4)*4 + reg.
template <int K, int NOUT, int H, typename AT>
__global__ __launch_bounds__(256) void gemm_att_mfma(
    const AT* __restrict__ A, const __half* __restrict__ WTg,
    const float* __restrict__ att_s, const float* __restrict__ att_d,
    __half* __restrict__ Y, float* __restrict__ AS, float* __restrict__ AD, int M) {
  constexpr int KK = K / 32;       // mfma K-steps
  constexpr int NT = NOUT / 16;    // 16-col tiles
  constexpr int NTH = NT / H;      // tiles per head
  constexpr int LDW = K + 8;       // padded WT row (halfs)
  constexpr int LDY = NOUT + 8;    // padded Y row (halfs)
  __shared__ __half wts[NOUT * LDW];
  __shared__ __half ylds[4][16 * LDY];

  int tid = threadIdx.x;
  int w = tid >> 6;
  int lane = tid & 63;
  int lrow = lane & 15;   // A row / D col within tile
  int lch = lane >> 4;    // k-chunk 0..3
  int r0w = blockIdx.x * 64 + w * 16;
  bool active = (r0w < M);  // wave-uniform; M % 16 == 0 so no partial waves

  // stage WT into LDS (coalesced global, padded rows)
  constexpr int RCH = K / 8;  // uint4 chunks per WT row
  for (int idx = tid; idx < NOUT * RCH; idx += 256) {
    int c = idx / RCH, ch = idx % RCH;
    *(uint4*)&wts[c * LDW + ch * 8] = ((const uint4*)WTg)[idx];
  }
  __syncthreads();

  f32x4 acc[NT];
#pragma unroll
  for (int nt = 0; nt < NT; nt++) acc[nt] = (f32x4){0.f, 0.f, 0.f, 0.f};

  if (active) {
    // A fragments
    half8 afrag[KK];
    if constexpr (sizeof(AT) == 4) {
      const float* arow = (const float*)A + (size_t)(r0w + lrow) * K + lch * 8;
#pragma unroll
      for (int kk = 0; kk < KK; kk++) {
        float4 v0 = *(const float4*)(arow + kk * 32);
        float4 v1 = *(const float4*)(arow + kk * 32 + 4);
        half8 a;
        a[0] = (_Float16)v0.x; a[1] = (_Float16)v0.y;
        a[2] = (_Float16)v0.z; a[3] = (_Float16)v0.w;
        a[4] = (_Float16)v1.x; a[5] = (_Float16)v1.y;
        a[6] = (_Float16)v1.z; a[7] = (_Float16)v1.w;
        afrag[kk] = a;
      }
    } else {
      const __half* arow = (const __half*)A + (size_t)(r0w + lrow) * K + lch * 8;
#pragma unroll
      for (int kk = 0; kk < KK; kk++) afrag[kk] = *(const half8*)(arow + kk * 32);
    }

#pragma unroll
    for (int kk = 0; kk < KK; kk++) {
#pragma unroll
      for (int nt = 0; nt < NT; nt++) {
        half8 b = *(const half8*)&wts[(nt * 16 + lrow) * LDW + kk * 32 + lch * 8];
        acc[nt] = __builtin_amdgcn_mfma_f32_16x16x32_f16(afrag[kk], b, acc[nt], 0, 0, 0);
      }
    }

    // attention dots from fp32 accumulators (exact)
    float asw[NT], adw[NT];
#pragma unroll
    for (int nt = 0; nt < NT; nt++) {
      asw[nt] = att_s[nt * 16 + lrow];
      adw[nt] = att_d[nt * 16 + lrow];
    }
#pragma unroll
    for (int h = 0; h < H; h++) {
#pragma unroll
      for (int reg = 0; reg < 4; reg++) {
        float ps = 0.f, pd = 0.f;
#pragma unroll
        for (int nt = h * NTH; nt < (h + 1) * NTH; nt++) {
          ps = fmaf(acc[nt][reg], asw[nt], ps);
          pd = fmaf(acc[nt][reg], adw[nt], pd);
        }
#pragma unroll
        for (int o = 1; o < 16; o <<= 1) {
          ps += __shfl_xor(ps, o);
          pd += __shfl_xor(pd, o);
        }
        if (lrow == 0) {
          int row = r0w + lch * 4 + reg;
          AS[row * H + h] = ps;
          AD[row * H + h] = pd;
        }
      }
    }

    // stage Y tile to LDS (D layout: row = lch*4+reg, col = nt*16+lrow)
#pragma unroll
    for (int nt = 0; nt < NT; nt++) {
#pragma unroll
      for (int reg = 0; reg < 4; reg++) {
        ylds[w][(lch * 4 + reg) * LDY + nt * 16 + lrow] = __float2half(acc[nt][reg]);
      }
    }
  }
  __syncthreads();

  if (active) {
    // coalesced Y store: consecutive lanes -> consecutive 16B chunks
    constexpr int YCH = NOUT / 8;  // uint4 chunks per row
    for (int idx = lane; idx < 16 * YCH; idx += 64) {
      int row = idx / YCH, ch = idx % YCH;
      uint4 v = *(const uint4*)&ylds[w][row * LDY + ch * 8];
      *(uint4*)(Y + (size_t)(r0w + row) * NOUT + ch * 8) = v;
    }
  }
}

// ---------------- node softmax + aggregate ----------------

static __device__ __forceinline__ void fma8(uint4 u, float e, float* __restrict__ acc) {
  float2 f0 = __half22float2(*(const __half2*)&u.x);
  float2 f1 = __half22float2(*(((const __half2*)&u.x) + 1));
  float2 f2 = __half22float2(*(const __half2*)&u.z);
  float2 f3 = __half22float2(*(((const __half2*)&u.z) + 1));
  acc[0] = fmaf(e, f0.x, acc[0]); acc[1] = fmaf(e, f0.y, acc[1]);
  acc[2] = fmaf(e, f1.x, acc[2]); acc[3] = fmaf(e, f1.y, acc[3]);
  acc[4] = fmaf(e, f2.x, acc[4]); acc[5] = fmaf(e, f2.y, acc[5]);
  acc[6] = fmaf(e, f3.x, acc[6]); acc[7] = fmaf(e, f3.y, acc[7]);
}

// 256-thread blocks, 4 waves; wave w handles node blockIdx*NPB + w/H, head w%H.
template <int H, int NPB, bool RELU, typename OT>
__global__ void node_kernel(const int* __restrict__ offsets, const int* __restrict__ csr_src,
                            const float* __restrict__ AS, const float* __restrict__ AD,
                            const __half* __restrict__ XPH, const float* __restrict__ bias,
                            OT* __restrict__ OUT, int Nn) {
  constexpr int C = 64;
  constexpr int ROWH = H * C;
  int w = threadIdx.x >> 6;
  int n = blockIdx.x * NPB + (w / H);
  int h = w % H;
  if (n >= Nn) return;  // wave-uniform; no block-wide barriers below
  int lane = threadIdx.x & 63;
  int g = lane >> 3;
  int sub = lane & 7;

  int beg = offsets[n], end = offsets[n + 1];
  int deg = end - beg;

  float ad_n = AD[n * H + h];
  const __half* base = XPH + h * C + sub * 8;

  float acc[8];
#pragma unroll
  for (int k = 0; k < 8; k++) acc[k] = 0.f;
  float z = 0.f;

  float e_self = __expf(lrelu(AS[n * H + h] + ad_n));
  if (g == 0) {
    uint4 u = *(const uint4*)(base + (size_t)n * ROWH);
    fma8(u, e_self, acc);
  }
  if (lane == 0) z = e_self;

  for (int i0 = 0; i0 < deg; i0 += 64) {
    int cnt = min(64, deg - i0);
    int srcv = 0;
    float ev = 0.f;
    if (lane < cnt) {
      srcv = csr_src[beg + i0 + lane];
      ev = __expf(lrelu(AS[srcv * H + h] + ad_n));
    }
    z += ev;
    int j = 0;
    for (; j + 32 <= cnt; j += 32) {
      int s0 = __shfl(srcv, j + g),      s1 = __shfl(srcv, j + 8 + g);
      int s2 = __shfl(srcv, j + 16 + g), s3 = __shfl(srcv, j + 24 + g);
      float e0 = __shfl(ev, j + g),      e1 = __shfl(ev, j + 8 + g);
      float e2 = __shfl(ev, j + 16 + g), e3 = __shfl(ev, j + 24 + g);
      uint4 u0 = *(const uint4*)(base + (size_t)s0 * ROWH);
      uint4 u1 = *(const uint4*)(base + (size_t)s1 * ROWH);
      uint4 u2 = *(const uint4*)(base + (size_t)s2 * ROWH);
      uint4 u3 = *(const uint4*)(base + (size_t)s3 * ROWH);
      fma8(u0, e0, acc);
      fma8(u1, e1, acc);
      fma8(u2, e2, acc);
      fma8(u3, e3, acc);
    }
    for (; j + 8 <= cnt; j += 8) {
      int s = __shfl(srcv, j + g);
      float e = __shfl(ev, j + g);
      uint4 u = *(const uint4*)(base + (size_t)s * ROWH);
      fma8(u, e, acc);
    }
    if (j < cnt) {
      int idx = j + g;
      int s = __shfl(srcv, idx & 63);
      float e = __shfl(ev, idx & 63);
      if (idx < cnt) {
        uint4 u = *(const uint4*)(base + (size_t)s * ROWH);
        fma8(u, e, acc);
      }
    }
  }

#pragma unroll
  for (int o = 8; o <= 32; o <<= 1) {
#pragma unroll
    for (int k = 0; k < 8; k++) acc[k] += __shfl_xor(acc[k], o);
  }
  for (int o = 32; o > 0; o >>= 1) z += __shfl_xor(z, o);
  float inv = 1.0f / z;

  if (g == 0) {
    const float* bp = bias + h * C + sub * 8;
    float r[8];
#pragma unroll
    for (int k = 0; k < 8; k++) {
      r[k] = fmaf(acc[k], inv, bp[k]);
      if (RELU) r[k] = fmaxf(r[k], 0.f);
    }
    if constexpr (sizeof(OT) == 4) {
      float* op = (float*)OUT + (size_t)n * ROWH + h * C + sub * 8;
      ((float4*)op)[0] = make_float4(r[0], r[1], r[2], r[3]);
      ((float4*)op)[1] = make_float4(r[4], r[5], r[6], r[7]);
    } else {
      __half* op = (__half*)OUT + (size_t)n * ROWH + h * C + sub * 8;
      __half2 h0 = __floats2half2_rn(r[0], r[1]);
      __half2 h1 = __floats2half2_rn(r[2], r[3]);
      __half2 h2 = __floats2half2_rn(r[4], r[5]);
      __half2 h3 = __floats2half2_rn(r[6], r[7]);
      uint4 u;
      u.x = *(unsigned int*)&h0; u.y = *(unsigned int*)&h1;
      u.z = *(unsigned int*)&h2; u.w = *(unsigned int*)&h3;
      *(uint4*)op = u;
    }
  }
}

// ---------------- launch ----------------

static inline size_t alignup(size_t x) { return (x + 255) & ~(size_t)255; }

extern "C" void kernel_launch(void* const* d_in, const int* in_sizes, int n_in,
                              void* d_out, int out_size, void* d_ws, size_t ws_size,
                              hipStream_t stream) {
  const float* x    = (const float*)d_in[0];
  const int*   edges= (const int*)d_in[1];
  const float* W1   = (const float*)d_in[2];
  const float* as1w = (const float*)d_in[3];
  const float* ad1w = (const float*)d_in[4];
  const float* b1   = (const float*)d_in[5];
  const float* W2   = (const float*)d_in[6];
  const float* as2w = (const float*)d_in[7];
  const float* ad2w = (const float*)d_in[8];
  const float* b2   = (const float*)d_in[9];

  const int N = in_sizes[0] / 128;   // 50000
  const int E = in_sizes[1] / 2;     // 1600000
  const int* src = edges;
  const int* dst = edges + E;
  const int nbk = (N + 255) >> 8;    // 196 buckets

  char* p = (char*)d_ws;
  size_t off = 0;
  auto take = [&](size_t bytes) { char* r = p + off; off = alignup(off + bytes); return r; };
  __half* xph1 = (__half*)take((size_t)N * 128 * 2);
  __half* xph2 = (__half*)take((size_t)N * 64 * 2);
  __half* hbuf = (__half*)take((size_t)N * 128 * 2);
  __half* wt1  = (__half*)take((size_t)128 * 128 * 2);
  __half* wt2  = (__half*)take((size_t)64 * 128 * 2);
  float* as1   = (float*)take((size_t)N * 2 * 4);
  float* ad1   = (float*)take((size_t)N * 2 * 4);
  float* as2   = (float*)take((size_t)N * 4);
  float* ad2   = (float*)take((size_t)N * 4);
  int* offsets = (int*)take((size_t)(N + 1) * 4);
  int* csr_src = (int*)take((size_t)E * 4);
  unsigned int* binned = (unsigned int*)take((size_t)E * 4);
  int* bcount  = (int*)take((size_t)(nbk + 1) * 4);
  int* bbase   = (int*)take((size_t)(nbk + 1) * 4);
  int* bcursor = (int*)take((size_t)(nbk + 1) * 4);
  (void)ws_size;

  constexpr int CHUNK = 8192;
  const int binBlocks = (E + CHUNK - 1) / CHUNK;
  const int gemmBlocks = (N + 63) / 64;

  hipMemsetAsync(bcount, 0, (size_t)(nbk + 1) * 4, stream);
  bucket_hist<<<392, 256, 0, stream>>>(dst, bcount, E, nbk);
  bucket_scan<<<1, 256, 0, stream>>>(bcount, bbase, bcursor, nbk, E);
  bin_kernel<CHUNK><<<binBlocks, 256, 0, stream>>>(src, dst, bcursor, binned, E, nbk);
  build_kernel<12288><<<nbk, 256, 0, stream>>>(binned, bbase, offsets, csr_src, N, E, nbk);

  xpose_w<<<2, 256, 0, stream>>>(W1, W2, wt1, wt2);

  // layer 1 (H=2, C=64, ReLU): x fp32 -> MFMA -> xph1 fp16 + as1/ad1 fp32
  gemm_att_mfma<128, 128, 2, float><<<gemmBlocks, 256, 0, stream>>>(
      x, wt1, as1w, ad1w, xph1, as1, ad1, N);
  node_kernel<2, 2, true, __half><<<(N + 1) / 2, 256, 0, stream>>>(
      offsets, csr_src, as1, ad1, xph1, b1, hbuf, N);

  // layer 2 (H=1, C=64): hbuf fp16 -> MFMA -> xph2 fp16 + as2/ad2 fp32
  gemm_att_mfma<128, 64, 1, __half><<<gemmBlocks, 256, 0, stream>>>(
      hbuf, wt2, as2w, ad2w, xph2, as2, ad2, N);
  node_kernel<1, 4, false, float><<<(N + 3) / 4, 256, 0, stream>>>(
      offsets, csr_src, as2, ad2, xph2, b2, (float*)d_out, N);
}

// Round 8
// 183.064 us; speedup vs baseline: 1.4711x; 1.0652x over previous
//
#include <hip/hip_runtime.h>
#include <hip/hip_bf16.h>
#include <hip/hip_fp16.h>

// GAT 2-layer forward for MI355X — round 8.
// Changes vs round 7 (node kernels only):
//  - revert r6's multi-node blocks: 1 node/block (H=2: 128 thr, H=1: 64 thr);
//    NPB coupling cost ~10% makespan (block waits on slower node).
//  - inner gather loop accumulates in half2 via __hfma2 (v_pk_fma_f16):
//    4 pk-FMAs per 16B load instead of 4 cvt + 8 fp32 FMA; flushed to fp32
//    accumulators once per 32-edge iteration (<=4 fp16-chained terms).
//  - per-edge e shuffled as a packed half2 (same shuffle count as before).

#define SLOPE 0.2f
static __device__ __forceinline__ float lrelu(float a) { return a > 0.f ? a : SLOPE * a; }

#define NBK_MAX 256  // max buckets (N <= 65536)

typedef _Float16 half8 __attribute__((ext_vector_type(8)));
typedef float f32x4 __attribute__((ext_vector_type(4)));

// ---------------- CSR build (bucketed) ----------------

__global__ void bucket_hist(const int* __restrict__ dst, int* __restrict__ bucket_count,
                            int E, int nbk) {
  __shared__ int h[NBK_MAX];
  for (int i = threadIdx.x; i < nbk; i += blockDim.x) h[i] = 0;
  __syncthreads();
  int stride = gridDim.x * blockDim.x;
  for (int e = blockIdx.x * blockDim.x + threadIdx.x; e < E; e += stride)
    atomicAdd(&h[dst[e] >> 8], 1);
  __syncthreads();
  for (int i = threadIdx.x; i < nbk; i += blockDim.x)
    if (h[i]) atomicAdd(&bucket_count[i], h[i]);
}

__global__ void bucket_scan(const int* __restrict__ bucket_count, int* __restrict__ bucket_base,
                            int* __restrict__ bucket_cursor, int nbk, int Etot) {
  __shared__ int sh[256];
  int t = threadIdx.x;
  int v = (t < nbk) ? bucket_count[t] : 0;
  sh[t] = v;
  __syncthreads();
  for (int o = 1; o < 256; o <<= 1) {
    int u = (t >= o) ? sh[t - o] : 0;
    __syncthreads();
    sh[t] += u;
    __syncthreads();
  }
  int excl = sh[t] - v;
  if (t < nbk) { bucket_base[t] = excl; bucket_cursor[t] = excl; }
  if (t == 0) bucket_base[nbk] = Etot;
}

template <int CHUNK>  // 8192 = 256 threads x 32
__global__ void bin_kernel(const int* __restrict__ src, const int* __restrict__ dst,
                           int* __restrict__ bucket_cursor, unsigned int* __restrict__ binned,
                           int E, int nbk) {
  constexpr int PT = CHUNK / 256;
  __shared__ int hist[NBK_MAX];
  __shared__ int lbase[NBK_MAX];
  __shared__ int lcur[NBK_MAX];
  __shared__ int gpos[NBK_MAX];
  __shared__ unsigned int stage[CHUNK];
  __shared__ int sh[256];
  int t = threadIdx.x;
  int e0 = blockIdx.x * CHUNK;
  int cnt = min(CHUNK, E - e0);

  for (int i = t; i < nbk; i += 256) hist[i] = 0;
  __syncthreads();

  unsigned int pk[PT];
#pragma unroll
  for (int i = 0; i < PT; i++) {
    int e = e0 + t + i * 256;
    if (e < E) {
      int s = src[e], d = dst[e];
      int b = d >> 8;
      pk[i] = ((unsigned)b << 24) | ((unsigned)s << 8) | (unsigned)(d & 255);
      atomicAdd(&hist[b], 1);
    } else {
      pk[i] = 0xFFFFFFFFu;
    }
  }
  __syncthreads();

  int hv = (t < nbk) ? hist[t] : 0;
  sh[t] = hv;
  __syncthreads();
  for (int o = 1; o < 256; o <<= 1) {
    int u = (t >= o) ? sh[t - o] : 0;
    __syncthreads();
    sh[t] += u;
    __syncthreads();
  }
  if (t < nbk) {
    lbase[t] = sh[t] - hv;
    lcur[t] = sh[t] - hv;
    gpos[t] = hv ? atomicAdd(&bucket_cursor[t], hv) : 0;
  }
  __syncthreads();

#pragma unroll
  for (int i = 0; i < PT; i++) {
    if (pk[i] != 0xFFFFFFFFu) {
      int b = pk[i] >> 24;
      int lp = atomicAdd(&lcur[b], 1);
      stage[lp] = pk[i];
    }
  }
  __syncthreads();

  for (int i = t; i < cnt; i += 256) {
    unsigned int v = stage[i];
    int b = v >> 24;
    binned[gpos[b] + (i - lbase[b])] = v;
  }
}

template <int CAP>  // 12288
__global__ void build_kernel(const unsigned int* __restrict__ binned,
                             const int* __restrict__ bucket_base, int* __restrict__ offsets,
                             int* __restrict__ csr_src, int Nn, int Etot, int nbk) {
  __shared__ int nhist[256];
  __shared__ int sh[256];
  __shared__ int lcur[256];
  __shared__ unsigned short stage[CAP];
  int b = blockIdx.x;
  int t = threadIdx.x;
  int base = bucket_base[b];
  int sz = bucket_base[b + 1] - base;

  nhist[t] = 0;
  __syncthreads();
  for (int i = t; i < sz; i += 256) atomicAdd(&nhist[binned[base + i] & 255], 1);
  __syncthreads();

  int hv = nhist[t];
  sh[t] = hv;
  __syncthreads();
  for (int o = 1; o < 256; o <<= 1) {
    int u = (t >= o) ? sh[t - o] : 0;
    __syncthreads();
    sh[t] += u;
    __syncthreads();
  }
  int excl = sh[t] - hv;
  int node = (b << 8) + t;
  if (node < Nn) offsets[node] = base + excl;
  if (b == nbk - 1 && t == 0) offsets[Nn] = Etot;
  lcur[t] = excl;
  __syncthreads();

  if (sz <= CAP) {
    for (int i = t; i < sz; i += 256) {
      unsigned int v = binned[base + i];
      int lp = atomicAdd(&lcur[v & 255], 1);
      stage[lp] = (unsigned short)((v >> 8) & 0xFFFFu);
    }
    __syncthreads();
    for (int i = t; i < sz; i += 256) csr_src[base + i] = (int)stage[i];
  } else {
    for (int i = t; i < sz; i += 256) {
      unsigned int v = binned[base + i];
      int lp = atomicAdd(&lcur[v & 255], 1);
      csr_src[base + lp] = (int)((v >> 8) & 0xFFFFu);
    }
  }
}

// ---------------- weight transpose to fp16 ----------------

__global__ void xpose_w(const float* __restrict__ W1, const float* __restrict__ W2,
                        __half* __restrict__ WT1, __half* __restrict__ WT2) {
  int t = threadIdx.x;
  if (blockIdx.x == 0) {
    for (int idx = t; idx < 128 * 128; idx += 256) {
      int c = idx >> 7, k = idx & 127;
      WT1[idx] = __float2half(W1[k * 128 + c]);
    }
  } else {
    for (int idx = t; idx < 64 * 128; idx += 256) {
      int c = idx >> 7, k = idx & 127;
      WT2[idx] = __float2half(W2[k * 64 + c]);
    }
  }
}

// ---------------- MFMA GEMM + fused attention dots ----------------

template <int K, int NOUT, int H, typename AT>
__global__ __launch_bounds__(256) void gemm_att_mfma(
    const AT* __restrict__ A, const __half* __restrict__ WTg,
    const float* __restrict__ att_s, const float* __restrict__ att_d,
    __half* __restrict__ Y, float* __restrict__ AS, float* __restrict__ AD, int M) {
  constexpr int KK = K / 32;
  constexpr int NT = NOUT / 16;
  constexpr int NTH = NT / H;
  constexpr int LDW = K + 8;
  constexpr int LDY = NOUT + 8;
  __shared__ __half wts[NOUT * LDW];
  __shared__ __half ylds[4][16 * LDY];

  int tid = threadIdx.x;
  int w = tid >> 6;
  int lane = tid & 63;
  int lrow = lane & 15;
  int lch = lane >> 4;
  int r0w = blockIdx.x * 64 + w * 16;
  bool active = (r0w < M);

  constexpr int RCH = K / 8;
  for (int idx = tid; idx < NOUT * RCH; idx += 256) {
    int c = idx / RCH, ch = idx % RCH;
    *(uint4*)&wts[c * LDW + ch * 8] = ((const uint4*)WTg)[idx];
  }
  __syncthreads();

  f32x4 acc[NT];
#pragma unroll
  for (int nt = 0; nt < NT; nt++) acc[nt] = (f32x4){0.f, 0.f, 0.f, 0.f};

  if (active) {
    half8 afrag[KK];
    if constexpr (sizeof(AT) == 4) {
      const float* arow = (const float*)A + (size_t)(r0w + lrow) * K + lch * 8;
#pragma unroll
      for (int kk = 0; kk < KK; kk++) {
        float4 v0 = *(const float4*)(arow + kk * 32);
        float4 v1 = *(const float4*)(arow + kk * 32 + 4);
        half8 a;
        a[0] = (_Float16)v0.x; a[1] = (_Float16)v0.y;
        a[2] = (_Float16)v0.z; a[3] = (_Float16)v0.w;
        a[4] = (_Float16)v1.x; a[5] = (_Float16)v1.y;
        a[6] = (_Float16)v1.z; a[7] = (_Float16)v1.w;
        afrag[kk] = a;
      }
    } else {
      const __half* arow = (const __half*)A + (size_t)(r0w + lrow) * K + lch * 8;
#pragma unroll
      for (int kk = 0; kk < KK; kk++) afrag[kk] = *(const half8*)(arow + kk * 32);
    }

#pragma unroll
    for (int kk = 0; kk < KK; kk++) {
#pragma unroll
      for (int nt = 0; nt < NT; nt++) {
        half8 b = *(const half8*)&wts[(nt * 16 + lrow) * LDW + kk * 32 + lch * 8];
        acc[nt] = __builtin_amdgcn_mfma_f32_16x16x32_f16(afrag[kk], b, acc[nt], 0, 0, 0);
      }
    }

    float asw[NT], adw[NT];
#pragma unroll
    for (int nt = 0; nt < NT; nt++) {
      asw[nt] = att_s[nt * 16 + lrow];
      adw[nt] = att_d[nt * 16 + lrow];
    }
#pragma unroll
    for (int h = 0; h < H; h++) {
#pragma unroll
      for (int reg = 0; reg < 4; reg++) {
        float ps = 0.f, pd = 0.f;
#pragma unroll
        for (int nt = h * NTH; nt < (h + 1) * NTH; nt++) {
          ps = fmaf(acc[nt][reg], asw[nt], ps);
          pd = fmaf(acc[nt][reg], adw[nt], pd);
        }
#pragma unroll
        for (int o = 1; o < 16; o <<= 1) {
          ps += __shfl_xor(ps, o);
          pd += __shfl_xor(pd, o);
        }
        if (lrow == 0) {
          int row = r0w + lch * 4 + reg;
          AS[row * H + h] = ps;
          AD[row * H + h] = pd;
        }
      }
    }

#pragma unroll
    for (int nt = 0; nt < NT; nt++) {
#pragma unroll
      for (int reg = 0; reg < 4; reg++) {
        ylds[w][(lch * 4 + reg) * LDY + nt * 16 + lrow] = __float2half(acc[nt][reg]);
      }
    }
  }
  __syncthreads();

  if (active) {
    constexpr int YCH = NOUT / 8;
    for (int idx = lane; idx < 16 * YCH; idx += 64) {
      int row = idx / YCH, ch = idx % YCH;
      uint4 v = *(const uint4*)&ylds[w][row * LDY + ch * 8];
      *(uint4*)(Y + (size_t)(r0w + row) * NOUT + ch * 8) = v;
    }
  }
}

// ---------------- node softmax + aggregate ----------------

static __device__ __forceinline__ void fma8(uint4 u, float e, float* __restrict__ acc) {
  float2 f0 = __half22float2(*(const __half2*)&u.x);
  float2 f1 = __half22float2(*(((const __half2*)&u.x) + 1));
  float2 f2 = __half22float2(*(const __half2*)&u.z);
  float2 f3 = __half22float2(*(((const __half2*)&u.z) + 1));
  acc[0] = fmaf(e, f0.x, acc[0]); acc[1] = fmaf(e, f0.y, acc[1]);
  acc[2] = fmaf(e, f1.x, acc[2]); acc[3] = fmaf(e, f1.y, acc[3]);
  acc[4] = fmaf(e, f2.x, acc[4]); acc[5] = fmaf(e, f2.y, acc[5]);
  acc[6] = fmaf(e, f3.x, acc[6]); acc[7] = fmaf(e, f3.y, acc[7]);
}

static __device__ __forceinline__ void pk4(uint4 u, unsigned ep, __half2* __restrict__ acc2) {
  __half2 e2 = *(const __half2*)&ep;
  acc2[0] = __hfma2(e2, *(const __half2*)&u.x, acc2[0]);
  acc2[1] = __hfma2(e2, *(((const __half2*)&u.x) + 1), acc2[1]);
  acc2[2] = __hfma2(e2, *(const __half2*)&u.z, acc2[2]);
  acc2[3] = __hfma2(e2, *(((const __half2*)&u.z) + 1), acc2[3]);
}

// One block per node; wave = head (H*64 threads). 8 groups of 8 lanes; lane owns
// 8 channels (one dwordx4 fp16). Main loop: 32 edges/iter, half2 accumulation
// flushed to fp32 each iteration.
template <int H, bool RELU, typename OT>
__global__ void node_kernel(const int* __restrict__ offsets, const int* __restrict__ csr_src,
                            const float* __restrict__ AS, const float* __restrict__ AD,
                            const __half* __restrict__ XPH, const float* __restrict__ bias,
                            OT* __restrict__ OUT, int Nn) {
  constexpr int C = 64;
  constexpr int ROWH = H * C;
  int n = blockIdx.x;
  int h = threadIdx.x >> 6;
  int lane = threadIdx.x & 63;
  int g = lane >> 3;
  int sub = lane & 7;

  int beg = offsets[n], end = offsets[n + 1];
  int deg = end - beg;

  float ad_n = AD[n * H + h];
  const __half* base = XPH + h * C + sub * 8;

  float acc[8];
#pragma unroll
  for (int k = 0; k < 8; k++) acc[k] = 0.f;
  float z = 0.f;

  float e_self = __expf(lrelu(AS[n * H + h] + ad_n));
  if (g == 0) {
    uint4 u = *(const uint4*)(base + (size_t)n * ROWH);
    fma8(u, e_self, acc);
  }
  if (lane == 0) z = e_self;

  for (int i0 = 0; i0 < deg; i0 += 64) {
    int cnt = min(64, deg - i0);
    int srcv = 0;
    float ev = 0.f;
    int epk = 0;
    if (lane < cnt) {
      srcv = csr_src[beg + i0 + lane];
      ev = __expf(lrelu(AS[srcv * H + h] + ad_n));
      __half eh = __float2half(ev);
      unsigned short us = *(const unsigned short*)&eh;
      epk = (int)(((unsigned)us << 16) | us);
    }
    z += ev;
    int j = 0;
    for (; j + 32 <= cnt; j += 32) {
      int s0 = __shfl(srcv, j + g),      s1 = __shfl(srcv, j + 8 + g);
      int s2 = __shfl(srcv, j + 16 + g), s3 = __shfl(srcv, j + 24 + g);
      int p0 = __shfl(epk, j + g),       p1 = __shfl(epk, j + 8 + g);
      int p2 = __shfl(epk, j + 16 + g),  p3 = __shfl(epk, j + 24 + g);
      uint4 u0 = *(const uint4*)(base + (size_t)s0 * ROWH);
      uint4 u1 = *(const uint4*)(base + (size_t)s1 * ROWH);
      uint4 u2 = *(const uint4*)(base + (size_t)s2 * ROWH);
      uint4 u3 = *(const uint4*)(base + (size_t)s3 * ROWH);
      __half2 acc2[4];
      acc2[0] = __half2(__half(0.f), __half(0.f));
      acc2[1] = acc2[0]; acc2[2] = acc2[0]; acc2[3] = acc2[0];
      pk4(u0, (unsigned)p0, acc2);
      pk4(u1, (unsigned)p1, acc2);
      pk4(u2, (unsigned)p2, acc2);
      pk4(u3, (unsigned)p3, acc2);
#pragma unroll
      for (int k = 0; k < 4; k++) {
        float2 f = __half22float2(acc2[k]);
        acc[2 * k] += f.x;
        acc[2 * k + 1] += f.y;
      }
    }
    for (; j + 8 <= cnt; j += 8) {
      int s = __shfl(srcv, j + g);
      float e = __shfl(ev, j + g);
      uint4 u = *(const uint4*)(base + (size_t)s * ROWH);
      fma8(u, e, acc);
    }
    if (j < cnt) {
      int idx = j + g;
      int s = __shfl(srcv, idx & 63);
      float e = __shfl(ev, idx & 63);
      if (idx < cnt) {
        uint4 u = *(const uint4*)(base + (size_t)s * ROWH);
        fma8(u, e, acc);
      }
    }
  }

#pragma unroll
  for (int o = 8; o <= 32; o <<= 1) {
#pragma unroll
    for (int k = 0; k < 8; k++) acc[k] += __shfl_xor(acc[k], o);
  }
  for (int o = 32; o > 0; o >>= 1) z += __shfl_xor(z, o);
  float inv = 1.0f / z;

  if (g == 0) {
    const float* bp = bias + h * C + sub * 8;
    float r[8];
#pragma unroll
    for (int k = 0; k < 8; k++) {
      r[k] = fmaf(acc[k], inv, bp[k]);
      if (RELU) r[k] = fmaxf(r[k], 0.f);
    }
    if constexpr (sizeof(OT) == 4) {
      float* op = (float*)OUT + (size_t)n * ROWH + h * C + sub * 8;
      ((float4*)op)[0] = make_float4(r[0], r[1], r[2], r[3]);
      ((float4*)op)[1] = make_float4(r[4], r[5], r[6], r[7]);
    } else {
      __half* op = (__half*)OUT + (size_t)n * ROWH + h * C + sub * 8;
      __half2 h0 = __floats2half2_rn(r[0], r[1]);
      __half2 h1 = __floats2half2_rn(r[2], r[3]);
      __half2 h2 = __floats2half2_rn(r[4], r[5]);
      __half2 h3 = __floats2half2_rn(r[6], r[7]);
      uint4 u;
      u.x = *(unsigned int*)&h0; u.y = *(unsigned int*)&h1;
      u.z = *(unsigned int*)&h2; u.w = *(unsigned int*)&h3;
      *(uint4*)op = u;
    }
  }
}

// ---------------- launch ----------------

static inline size_t alignup(size_t x) { return (x + 255) & ~(size_t)255; }

extern "C" void kernel_launch(void* const* d_in, const int* in_sizes, int n_in,
                              void* d_out, int out_size, void* d_ws, size_t ws_size,
                              hipStream_t stream) {
  const float* x    = (const float*)d_in[0];
  const int*   edges= (const int*)d_in[1];
  const float* W1   = (const float*)d_in[2];
  const float* as1w = (const float*)d_in[3];
  const float* ad1w = (const float*)d_in[4];
  const float* b1   = (const float*)d_in[5];
  const float* W2   = (const float*)d_in[6];
  const float* as2w = (const float*)d_in[7];
  const float* ad2w = (const float*)d_in[8];
  const float* b2   = (const float*)d_in[9];

  const int N = in_sizes[0] / 128;   // 50000
  const int E = in_sizes[1] / 2;     // 1600000
  const int* src = edges;
  const int* dst = edges + E;
  const int nbk = (N + 255) >> 8;    // 196 buckets

  char* p = (char*)d_ws;
  size_t off = 0;
  auto take = [&](size_t bytes) { char* r = p + off; off = alignup(off + bytes); return r; };
  __half* xph1 = (__half*)take((size_t)N * 128 * 2);
  __half* xph2 = (__half*)take((size_t)N * 64 * 2);
  __half* hbuf = (__half*)take((size_t)N * 128 * 2);
  __half* wt1  = (__half*)take((size_t)128 * 128 * 2);
  __half* wt2  = (__half*)take((size_t)64 * 128 * 2);
  float* as1   = (float*)take((size_t)N * 2 * 4);
  float* ad1   = (float*)take((size_t)N * 2 * 4);
  float* as2   = (float*)take((size_t)N * 4);
  float* ad2   = (float*)take((size_t)N * 4);
  int* offsets = (int*)take((size_t)(N + 1) * 4);
  int* csr_src = (int*)take((size_t)E * 4);
  unsigned int* binned = (unsigned int*)take((size_t)E * 4);
  int* bcount  = (int*)take((size_t)(nbk + 1) * 4);
  int* bbase   = (int*)take((size_t)(nbk + 1) * 4);
  int* bcursor = (int*)take((size_t)(nbk + 1) * 4);
  (void)ws_size;

  constexpr int CHUNK = 8192;
  const int binBlocks = (E + CHUNK - 1) / CHUNK;
  const int gemmBlocks = (N + 63) / 64;

  hipMemsetAsync(bcount, 0, (size_t)(nbk + 1) * 4, stream);
  bucket_hist<<<392, 256, 0, stream>>>(dst, bcount, E, nbk);
  bucket_scan<<<1, 256, 0, stream>>>(bcount, bbase, bcursor, nbk, E);
  bin_kernel<CHUNK><<<binBlocks, 256, 0, stream>>>(src, dst, bcursor, binned, E, nbk);
  build_kernel<12288><<<nbk, 256, 0, stream>>>(binned, bbase, offsets, csr_src, N, E, nbk);

  xpose_w<<<2, 256, 0, stream>>>(W1, W2, wt1, wt2);

  // layer 1 (H=2, C=64, ReLU)
  gemm_att_mfma<128, 128, 2, float><<<gemmBlocks, 256, 0, stream>>>(
      x, wt1, as1w, ad1w, xph1, as1, ad1, N);
  node_kernel<2, true, __half><<<N, 128, 0, stream>>>(
      offsets, csr_src, as1, ad1, xph1, b1, hbuf, N);

  // layer 2 (H=1, C=64)
  gemm_att_mfma<128, 64, 1, __half><<<gemmBlocks, 256, 0, stream>>>(
      hbuf, wt2, as2w, ad2w, xph2, as2, ad2, N);
  node_kernel<1, false, float><<<N, 64, 0, stream>>>(
      offsets, csr_src, as2, ad2, xph2, b2, (float*)d_out, N);
}